// Round 1
// baseline (752.793 us; speedup 1.0000x reference)
//
#include <hip/hip_runtime.h>
#include <cstdint>
#include <cstddef>

// Problem constants
#define BB 32
#define SS 2048
#define DD 1024
#define MM (BB * SS)   // 65536 rows of the big GEMM

typedef __bf16 bf16_t;
typedef __bf16 bf16x4 __attribute__((ext_vector_type(4)));
typedef __bf16 bf16x8 __attribute__((ext_vector_type(8)));
typedef float  f32x4  __attribute__((ext_vector_type(4)));

typedef __attribute__((address_space(1))) unsigned int gu32;
typedef __attribute__((address_space(3))) unsigned int lu32;

__device__ __forceinline__ void async_copy16(const void* g, void* l) {
  __builtin_amdgcn_global_load_lds((gu32*)g, (lu32*)l, 16, 0, 0);
}

// ---------------------------------------------------------------------------
// Kernel 1: W1_enc (fp32, [k][n]) -> W1T (bf16, [n][k])  (transpose + convert)
// 64x64 tiles via LDS, grid 256 blocks x 256 threads
// ---------------------------------------------------------------------------
__global__ __launch_bounds__(256) void conv_w1t_kernel(
    const float* __restrict__ W1, bf16_t* __restrict__ W1T) {
  __shared__ float tile[64][65];
  const int bk = (blockIdx.x & 15) * 64;   // k tile origin
  const int bn = (blockIdx.x >> 4) * 64;   // n tile origin
  const int tx = threadIdx.x & 63;
  const int ty = threadIdx.x >> 6;         // 0..3
#pragma unroll
  for (int i = 0; i < 16; ++i) {
    const int kr = i * 4 + ty;
    tile[kr][tx] = W1[(size_t)(bk + kr) * 1024 + bn + tx];
  }
  __syncthreads();
#pragma unroll
  for (int i = 0; i < 16; ++i) {
    const int nr = i * 4 + ty;
    W1T[(size_t)(bn + nr) * 1024 + bk + tx] = (bf16_t)tile[tx][nr];
  }
}

// ---------------------------------------------------------------------------
// Kernel 2: dec_proj[b][u] = h_dec[b,:] @ W1_dec[:,u] + b1[u]  (fp32)
// Also zero-inits e2 (it is accumulated by atomics in the fused GEMM).
// Grid 32 blocks (one per b) x 256 threads, each thread owns 4 u's.
// ---------------------------------------------------------------------------
__global__ __launch_bounds__(256) void dec_proj_kernel(
    const float* __restrict__ hDec, const float* __restrict__ W1,
    const float* __restrict__ b1, float* __restrict__ dp,
    float* __restrict__ e2) {
  const int b = blockIdx.x;
  const int t = threadIdx.x;
#pragma unroll
  for (int i = 0; i < 8; ++i) e2[b * 2048 + i * 256 + t] = 0.f;
  float a0 = 0.f, a1 = 0.f, a2 = 0.f, a3 = 0.f;
  const float* wd = W1 + 1024 * 1024;  // W1_dec = rows 1024..2047
  for (int k = 0; k < 1024; ++k) {
    const float hv = hDec[b * 1024 + k];
    const float* row = wd + (size_t)k * 1024 + t;
    a0 += hv * row[0];
    a1 += hv * row[256];
    a2 += hv * row[512];
    a3 += hv * row[768];
  }
  dp[b * 1024 + t]       = a0 + b1[t];
  dp[b * 1024 + t + 256] = a1 + b1[t + 256];
  dp[b * 1024 + t + 512] = a2 + b1[t + 512];
  dp[b * 1024 + t + 768] = a3 + b1[t + 768];
}

// ---------------------------------------------------------------------------
// Kernel 3: fused bf16 MFMA GEMM + tanh + W2 row-reduction -> e2 partials
//   rows m = b*2048+s (32 per block), cols n = units (512 per block half)
//   e2[m] += sum_n tanh(hEnc[m,:]@W1enc[:,n] + dp[b,n]) * W2[n]
// grid = 4096 (2048 m-blocks x 2 n-halves), 256 threads (4 waves).
// Wave w owns n-range [nh*512 + w*128, +128). KT=32.
// LDS: sB 32KB (n-major, 64B rows, 16B-chunk XOR swizzle), sA 2KB, sRed 512B.
// ---------------------------------------------------------------------------
__global__ __launch_bounds__(256, 4) void fused_gemm_kernel(
    const float* __restrict__ hEnc, const bf16_t* __restrict__ W1T,
    const float* __restrict__ dp, const float* __restrict__ W2,
    float* __restrict__ e2) {
  __shared__ bf16_t sB[512 * 32];
  __shared__ bf16_t sA[32 * 32];
  __shared__ float sRed[4][32];

  const int tid  = threadIdx.x;
  const int lane = tid & 63;
  const int wv   = tid >> 6;
  const int mblk = blockIdx.x >> 1;
  const int nh   = blockIdx.x & 1;
  const int m0   = mblk * 32;
  const int b    = m0 >> 11;            // 2048 rows per batch element

  const int col = lane & 15;            // MFMA col / frag row-within-16
  const int q   = lane >> 4;            // quad -> k-chunk
  const int swz = q ^ ((col >> 1) & 3); // XOR swizzle, lane-constant

  f32x4 acc[2][8];
#pragma unroll
  for (int mt = 0; mt < 2; ++mt)
#pragma unroll
    for (int nt = 0; nt < 8; ++nt)
      acc[mt][nt] = (f32x4){0.f, 0.f, 0.f, 0.f};

  // A staging: thread -> (row 0..31, 8B half-chunk 0..7)
  const int arow = tid >> 3;
  const int ahc  = tid & 7;
  const unsigned a_lds_off =
      arow * 64u + ((unsigned)((ahc >> 1) ^ ((arow >> 1) & 3)) << 4) + (ahc & 1) * 8u;
  const float* aG = hEnc + (size_t)(m0 + arow) * 1024 + ahc * 4;

  // B staging lane mapping: lane -> (row-in-16-slab, 16B chunk)
  const int brow_l = lane >> 2;
  const int bc     = lane & 3;

  char* sAc = (char*)sA;
  char* sBc = (char*)sB;
  const unsigned a_rd0 = (unsigned)(col * 64 + swz * 16);
  const unsigned b_rd0 = (unsigned)((wv * 128 + col) * 64 + swz * 16);

#pragma unroll 1
  for (int k0 = 0; k0 < 1024; k0 += 32) {
    // stage B: wave wv fills its own local rows [wv*128, wv*128+128)
#pragma unroll
    for (int i = 0; i < 8; ++i) {
      const int ln0 = wv * 128 + i * 16;          // wave-uniform slab base
      const int ln  = ln0 + brow_l;               // local n row this lane feeds
      const int n   = nh * 512 + ln;              // global n
      const int kp  = bc ^ ((ln >> 1) & 3);       // gather swizzled k-chunk
      async_copy16(W1T + (size_t)n * 1024 + k0 + kp * 8, sBc + ln0 * 64);
    }
    // stage A (fp32 -> bf16 convert in-register)
    {
      const float4 av = *(const float4*)(aG + k0);
      bf16x4 a4;
      a4[0] = (bf16_t)av.x; a4[1] = (bf16_t)av.y;
      a4[2] = (bf16_t)av.z; a4[3] = (bf16_t)av.w;
      *(bf16x4*)(sAc + a_lds_off) = a4;
    }
    __syncthreads();
    // compute: 2 A-frags x 8 B-frags -> 16 MFMA per wave per k-step
    const bf16x8 afrag0 = *(const bf16x8*)(sAc + a_rd0);
    const bf16x8 afrag1 = *(const bf16x8*)(sAc + a_rd0 + 16 * 64);
#pragma unroll
    for (int nt = 0; nt < 8; ++nt) {
      const bf16x8 bfrag = *(const bf16x8*)(sBc + b_rd0 + nt * 1024);
      acc[0][nt] = __builtin_amdgcn_mfma_f32_16x16x32_bf16(afrag0, bfrag, acc[0][nt], 0, 0, 0);
      acc[1][nt] = __builtin_amdgcn_mfma_f32_16x16x32_bf16(afrag1, bfrag, acc[1][nt], 0, 0, 0);
    }
    __syncthreads();
  }

  // Epilogue: x = acc + dp[b,n]; t = tanh(x); rs[row] += t * W2[n]
  float rs[2][4] = {{0.f, 0.f, 0.f, 0.f}, {0.f, 0.f, 0.f, 0.f}};
#pragma unroll
  for (int nt = 0; nt < 8; ++nt) {
    const int n = nh * 512 + wv * 128 + nt * 16 + col;
    const float dpn = dp[b * 1024 + n];
    const float w2n = W2[n];
#pragma unroll
    for (int mt = 0; mt < 2; ++mt)
#pragma unroll
      for (int r = 0; r < 4; ++r) {
        const float x = acc[mt][nt][r] + dpn;
        const float e = __expf(2.f * x);       // tanh(x) = 1 - 2/(e^{2x}+1)
        const float th = 1.f - 2.f / (e + 1.f);
        rs[mt][r] += th * w2n;
      }
  }
  // reduce across the 16 cols (lane bits 0..3)
#pragma unroll
  for (int off = 1; off < 16; off <<= 1)
#pragma unroll
    for (int mt = 0; mt < 2; ++mt)
#pragma unroll
      for (int r = 0; r < 4; ++r)
        rs[mt][r] += __shfl_xor(rs[mt][r], off, 64);
  if (col == 0) {
#pragma unroll
    for (int mt = 0; mt < 2; ++mt)
#pragma unroll
      for (int r = 0; r < 4; ++r)
        sRed[wv][mt * 16 + q * 4 + r] = rs[mt][r];
  }
  __syncthreads();
  if (tid < 32) {
    const float v = sRed[0][tid] + sRed[1][tid] + sRed[2][tid] + sRed[3][tid];
    atomicAdd(&e2[m0 + tid], v);   // two n-halves accumulate
  }
}

// ---------------------------------------------------------------------------
// Kernel 4: per-b softmax over S of relu(e2 + b2); writes attn weights to
// d_out, zeroes the context region (kernel 5 accumulates with atomics).
// ---------------------------------------------------------------------------
__global__ __launch_bounds__(256) void softmax_kernel(
    const float* __restrict__ e2, const float* __restrict__ b2,
    float* __restrict__ attn, float* __restrict__ ctx) {
  const int b = blockIdx.x;
  const int t = threadIdx.x;
  __shared__ float sred[4];
  const float b2v = b2[0];
  float v[8];
  float lmax = 0.f;  // relu output >= 0
#pragma unroll
  for (int i = 0; i < 8; ++i) {
    v[i] = fmaxf(e2[b * 2048 + i * 256 + t] + b2v, 0.f);  // energies2
    lmax = fmaxf(lmax, v[i]);
  }
#pragma unroll
  for (int off = 1; off < 64; off <<= 1) lmax = fmaxf(lmax, __shfl_xor(lmax, off, 64));
  const int wv = t >> 6;
  const int lane = t & 63;
  if (lane == 0) sred[wv] = lmax;
  __syncthreads();
  const float bmax = fmaxf(fmaxf(sred[0], sred[1]), fmaxf(sred[2], sred[3]));
  __syncthreads();
  float ev[8];
  float lsum = 0.f;
#pragma unroll
  for (int i = 0; i < 8; ++i) { ev[i] = __expf(v[i] - bmax); lsum += ev[i]; }
#pragma unroll
  for (int off = 1; off < 64; off <<= 1) lsum += __shfl_xor(lsum, off, 64);
  if (lane == 0) sred[wv] = lsum;
  __syncthreads();
  const float inv = 1.f / (sred[0] + sred[1] + sred[2] + sred[3]);
#pragma unroll
  for (int i = 0; i < 8; ++i) attn[b * 2048 + i * 256 + t] = ev[i] * inv;
#pragma unroll
  for (int i = 0; i < 4; ++i) ctx[b * 1024 + i * 256 + t] = 0.f;
}

// ---------------------------------------------------------------------------
// Kernel 5: context[b,d] = sum_s attn[b,s] * hEnc[b,s,d]
// grid = 32 b x 32 s-chunks(64), 256 threads x float4 covers d=1024.
// ---------------------------------------------------------------------------
__global__ __launch_bounds__(256) void context_kernel(
    const float* __restrict__ hEnc, const float* __restrict__ attn,
    float* __restrict__ ctx) {
  const int b = blockIdx.x >> 5;
  const int c = blockIdx.x & 31;
  const int t = threadIdx.x;
  __shared__ float w[64];
  if (t < 64) w[t] = attn[b * 2048 + c * 64 + t];
  __syncthreads();
  float ax = 0.f, ay = 0.f, az = 0.f, aw = 0.f;
  const float* base = hEnc + ((size_t)b * 2048 + c * 64) * 1024 + t * 4;
#pragma unroll 4
  for (int s = 0; s < 64; ++s) {
    const float4 h4 = *(const float4*)(base + (size_t)s * 1024);
    const float ws = w[s];
    ax += ws * h4.x; ay += ws * h4.y; az += ws * h4.z; aw += ws * h4.w;
  }
  float* o = ctx + b * 1024 + t * 4;
  atomicAdd(o + 0, ax);
  atomicAdd(o + 1, ay);
  atomicAdd(o + 2, az);
  atomicAdd(o + 3, aw);
}

// ---------------------------------------------------------------------------
extern "C" void kernel_launch(void* const* d_in, const int* in_sizes, int n_in,
                              void* d_out, int out_size, void* d_ws, size_t ws_size,
                              hipStream_t stream) {
  const float* hEnc = (const float*)d_in[0];  // (32,2048,1024) fp32
  const float* hDec = (const float*)d_in[1];  // (32,1024) fp32
  const float* W1   = (const float*)d_in[2];  // (2048,1024) fp32
  const float* b1   = (const float*)d_in[3];  // (1024,) fp32
  const float* W2   = (const float*)d_in[4];  // (1024,1) fp32
  const float* b2   = (const float*)d_in[5];  // (1,) fp32
  float* out = (float*)d_out;                 // [0,32768): context; [32768,98304): attn

  // workspace: W1T bf16 2MB | dp fp32 128KB | e2 fp32 256KB  (2.375 MB total)
  char* ws = (char*)d_ws;
  bf16_t* W1T = (bf16_t*)ws;
  float*  dp  = (float*)(ws + 2u * 1024 * 1024);
  float*  e2  = (float*)(ws + 2u * 1024 * 1024 + 128u * 1024);

  conv_w1t_kernel<<<256, 256, 0, stream>>>(W1, W1T);
  dec_proj_kernel<<<32, 256, 0, stream>>>(hDec, W1, b1, dp, e2);
  fused_gemm_kernel<<<4096, 256, 0, stream>>>(hEnc, W1T, dp, W2, e2);
  softmax_kernel<<<32, 256, 0, stream>>>(e2, b2, out + 32768, out);
  context_kernel<<<1024, 256, 0, stream>>>(hEnc, out + 32768, out);
}